// Round 17
// baseline (101.459 us; speedup 1.0000x reference)
//
#include <hip/hip_runtime.h>
#include <hip/hip_bf16.h>

// ---------------------------------------------------------------------------
// Diagonal-covariance GMM log-likelihoods as one bf16 MFMA GEMM + bias:
//   out[m,k] = sum_f [ x^2 * (-0.5/cov) + x * (mu/cov) ] + bias[k]
// GEMM: M=16384, N=512 (padded from 500), K2=2048 (interleaved x^2/x pairs)
//
// R16: in-block split-K. R10's cap was grid-geometric (512 blocks x 4 waves =
// 2 waves/SIMD); all routes to more waves so far either duplicated B x4 (R14)
// or blew the per-XCD X working set with more co-resident blocks (R7/R11/R15,
// FETCH 41->97MB). Here: 512-thread blocks, SAME grid 512 / SAME tile /
// SAME traffic: two 4-wave groups per block, group g computes the tile over
// K-half g (16 iters each; group structure identical to R10). 4 waves/SIMD
// with zero new global traffic. Epilogue: g1 dumps acc to 64KB LDS overlay,
// g0 adds acc+bias (RMW), then all 512 threads stream out coalesced.
// __launch_bounds__(512,4) caps 128 regs (acc64+B32+A16+addr~12) — WRITE_SIZE
// is the spill canary.
// ---------------------------------------------------------------------------

typedef __attribute__((ext_vector_type(8))) __bf16 bf16x8;
typedef __attribute__((ext_vector_type(4))) float  f32x4;

#define LOG_2PI 1.837877066409345339082f

constexpr int M_TOT = 16384;   // B*T
constexpr int F_DIM = 1024;
constexpr int K_GMM = 500;
constexpr int N_PAD = 512;

constexpr int BM  = 128;
constexpr int BN  = 128;
constexpr int BKF = 32;              // K-step in floats (=> 64 bf16 along K2)
constexpr int NIT = 16;              // per-group K-steps (2 groups x 16 = 32)

// pack (bf16(x*x), bf16(x)) into one dword: low16 = x^2 (even K2 slot), hi16 = x
__device__ __forceinline__ unsigned pack_sq_x(float x) {
    __hip_bfloat162 h = __float22bfloat162_rn(make_float2(x * x, x));
    union { __hip_bfloat162 h; unsigned u; } cv;
    cv.h = h;
    return cv.u;
}

// ---------------------------------------------------------------------------
// prep: build the FRAGMENT-MAJOR W image + fp32 bias. (unchanged from R10)
// Row k: tt=k>>7 (n_tile), wch=(k>>6)&1 (col-half), b=(k>>4)&3, lo=k&15.
// Row dword d: it=d>>5, c=(d>>4)&1, hi=(d>>2)&3, jj=d&3.
// Image dword addr = (((tt*2+wch)*32+it)*8 + (b*2+c))*256 + (hi*16+lo)*4 + jj.
// => per (tt,wch,it,frag) a contiguous 1KB block in exact lane order.
// Value: (bf16(-0.5/cov), bf16(mu/cov)); rows k>=500 zeroed, bias=0 there.
// ---------------------------------------------------------------------------
__global__ __launch_bounds__(256) void prep_w_kernel(
    const float* __restrict__ mu, const float* __restrict__ cov,
    unsigned* __restrict__ Wimg, float* __restrict__ bias)
{
    const int k = blockIdx.x;           // 0..511 (component row)
    const int t = threadIdx.x;
    const int tt  = k >> 7;
    const int wch = (k >> 6) & 1;
    const int b   = (k >> 4) & 3;
    const int lo  = k & 15;
    float sl = 0.f, sq = 0.f;
    #pragma unroll
    for (int j = 0; j < 4; ++j) {
        const int d  = t + j * 256;          // row dword index 0..1023
        const int it = d >> 5;
        const int c  = (d >> 4) & 1;
        const int hi = (d >> 2) & 3;
        const int jj = d & 3;
        const int dw = ((((tt * 2 + wch) * 32 + it) * 8) + (b * 2 + c)) * 256
                     + (hi * 16 + lo) * 4 + jj;
        if (k < K_GMM) {
            const float cv_ = cov[k * F_DIM + d];
            const float m_  = mu[k * F_DIM + d];
            const float ic  = 1.0f / cv_;
            __hip_bfloat162 h = __float22bfloat162_rn(make_float2(-0.5f * ic, m_ * ic));
            union { __hip_bfloat162 h; unsigned u; } cvt; cvt.h = h;
            Wimg[dw] = cvt.u;
            sl += logf(cv_);
            sq += m_ * m_ * ic;
        } else {
            Wimg[dw] = 0u;
        }
    }
    #pragma unroll
    for (int off = 32; off > 0; off >>= 1) {
        sl += __shfl_down(sl, off, 64);
        sq += __shfl_down(sq, off, 64);
    }
    __shared__ float red[8];
    if ((t & 63) == 0) { red[(t >> 6) * 2] = sl; red[(t >> 6) * 2 + 1] = sq; }
    __syncthreads();
    if (t == 0) {
        const float SL = red[0] + red[2] + red[4] + red[6];
        const float SQ = red[1] + red[3] + red[5] + red[7];
        bias[k] = (k < K_GMM)
                ? (-0.5f * (F_DIM * LOG_2PI) - 0.5f * SL - 0.5f * SQ) : 0.f;
    }
}

// ---------------------------------------------------------------------------
// GEMM: 128x128 tile, 512 threads = 2 K-groups x 4 waves (each wave 64x64).
// Group g covers K-steps g*16..g*16+15. LDS 64KB = 2 groups x A dbuf (16KB);
// epilogue overlays the full 64KB as a 128x128 fp32 tile.
// B: per-wave contiguous 1KB fragment loads (fragment-major image), single
// set refilled after consumption. One lgkm-only barrier per iteration (both
// groups share the s_barrier in lockstep).
// 512 blocks (2/CU -> 16 waves/CU = 4/SIMD); n-siblings 128 apart (same XCD).
// ---------------------------------------------------------------------------
__global__ __launch_bounds__(512, 4) void gemm_kernel(
    const float* __restrict__ X, const unsigned* __restrict__ Wimg,
    const float* __restrict__ bias, float* __restrict__ out)
{
    __shared__ __align__(16) char smem[65536];
    float* ep = reinterpret_cast<float*>(smem);   // 128x128 fp32 epilogue (64KB)

    const int bid    = blockIdx.x;
    const int m_base = (bid & 127) * BM;
    const int n_tile = bid >> 7;
    const int n_base = n_tile * BN;

    const int tid  = threadIdx.x;
    const int lane = tid & 63;
    const int wv   = tid >> 6;          // 0..7
    const int grp  = wv >> 2;           // K-group 0/1
    const int gw   = wv & 3;            // wave within group
    const int wr   = (gw >> 1) * 64;    // wave row block (0/64)
    const int wch  = gw & 1;            // wave col-half
    const int wc   = wch * 64;
    const int hi   = lane >> 4;         // 0..3
    const int lo   = lane & 15;
    const int lsw  = lo & 7;            // lane-constant fragment read swizzle
    const int kbase = grp * 16;         // group's first global K-step

    const int gtid = tid & 255;         // thread within group
    const int sr   = gtid >> 1;         // A staging row 0..127
    const int sh   = gtid & 1;          // staging half (chunks 0-3 / 4-7)

    const float4* Xv = reinterpret_cast<const float4*>(X);     // X row = 256 float4
    const bf16x8* Wf = reinterpret_cast<const bf16x8*>(Wimg);
    const int wbase = (n_tile * 2 + wch) * 32 * 8 * 64;        // bf16x8 units

    f32x4 acc[4][4];
    #pragma unroll
    for (int a = 0; a < 4; ++a)
        #pragma unroll
        for (int b = 0; b < 4; ++b)
            acc[a][b] = (f32x4){0.f, 0.f, 0.f, 0.f};

    auto loadA = [&](int itS, float4* ar) {           // 4 global float4 / thread
        #pragma unroll
        for (int j = 0; j < 4; ++j)
            ar[j] = Xv[(size_t)(m_base + sr) * (F_DIM / 4)
                       + (kbase + itS) * 8 + sh * 4 + j];
    };
    auto packA = [&](const float4* ar, int ab) {      // pack + swizzled ds_write
        unsigned short* Ad =
            reinterpret_cast<unsigned short*>(smem + grp * 32768 + ab * 16384);
        #pragma unroll
        for (int j = 0; j < 4; ++j) {
            const int chunk = (sh * 4 + j) ^ (sr & 7);
            uint4 wa;
            wa.x = pack_sq_x(ar[j].x);
            wa.y = pack_sq_x(ar[j].y);
            wa.z = pack_sq_x(ar[j].z);
            wa.w = pack_sq_x(ar[j].w);
            *reinterpret_cast<uint4*>(&Ad[sr * 64 + chunk * 8]) = wa;
        }
    };
    auto loadB = [&](int itS, bf16x8* br) {           // 8 contiguous 1KB wave-loads
        #pragma unroll
        for (int f = 0; f < 8; ++f)
            br[f] = Wf[wbase + ((kbase + itS) * 8 + f) * 64 + lane];
    };
    auto mfmas = [&](int ab, const bf16x8* br) {      // 8 ds_read_b128 + 32 MFMA
        const unsigned short* Asc =
            reinterpret_cast<const unsigned short*>(smem + grp * 32768 + ab * 16384);
        #pragma unroll
        for (int c = 0; c < 2; ++c) {
            bf16x8 af[4];
            #pragma unroll
            for (int a = 0; a < 4; ++a) {
                const int row   = wr + a * 16 + lo;
                const int chunk = (c * 4 + hi) ^ lsw;
                af[a] = *reinterpret_cast<const bf16x8*>(&Asc[row * 64 + chunk * 8]);
            }
            __builtin_amdgcn_s_setprio(1);
            #pragma unroll
            for (int a = 0; a < 4; ++a)
                #pragma unroll
                for (int b = 0; b < 4; ++b)
                    acc[a][b] = __builtin_amdgcn_mfma_f32_16x16x32_bf16(
                        af[a], br[b * 2 + c], acc[a][b], 0, 0, 0);
            __builtin_amdgcn_s_setprio(0);
        }
    };

    // ---- prologue ----
    float4 aA[4];
    bf16x8 bb[8];
    loadA(0, aA);
    loadB(0, bb);
    packA(aA, 0);          // waits only aA's own loads (reg deps)
    loadA(1, aA);          // A(1) in flight
    asm volatile("s_waitcnt lgkmcnt(0)" ::: "memory");
    __builtin_amdgcn_s_barrier();
    __builtin_amdgcn_sched_barrier(0);

    // ---- main loop: 16 iterations per group, one lgkm-only barrier each ----
    for (int it = 0; it < NIT; ++it) {
        const int ab = it & 1;
        if (it + 1 < NIT) {
            packA(aA, ab ^ 1);                 // A(it+1) -> other buffer
            if (it + 2 < NIT) loadA(it + 2, aA);
        }
        mfmas(ab, bb);
        if (it + 1 < NIT) loadB(it + 1, bb);   // refill after consume
        asm volatile("s_waitcnt lgkmcnt(0)" ::: "memory");
        __builtin_amdgcn_s_barrier();
        __builtin_amdgcn_sched_barrier(0);
    }

    // ---- Epilogue: g1 dumps acc; g0 adds acc+bias (RMW); all stream out ----
    // (final loop barrier separates last ds_reads from ep overwrite)
    if (grp == 1) {
        #pragma unroll
        for (int b = 0; b < 4; ++b) {
            const int col = wc + b * 16 + lo;
            #pragma unroll
            for (int a = 0; a < 4; ++a) {
                const int er = wr + a * 16 + hi * 4;  // D: col=lane&15, row=(lane>>4)*4+i
                #pragma unroll
                for (int i = 0; i < 4; ++i)
                    ep[(er + i) * 128 + col] = acc[a][b][i];
            }
        }
    }
    __syncthreads();
    if (grp == 0) {
        #pragma unroll
        for (int b = 0; b < 4; ++b) {
            const int col = wc + b * 16 + lo;
            const float bv = bias[n_base + col];
            #pragma unroll
            for (int a = 0; a < 4; ++a) {
                const int er = wr + a * 16 + hi * 4;
                #pragma unroll
                for (int i = 0; i < 4; ++i)
                    ep[(er + i) * 128 + col] += acc[a][b][i] + bv;
            }
        }
    }
    __syncthreads();

    const int ncols = (K_GMM - n_base < BN) ? (K_GMM - n_base) : BN;  // 128 or 116
    #pragma unroll
    for (int q = 0; q < 8; ++q) {
        const int f    = q * 512 + tid;   // float4 id in 128x32 grid
        const int row  = f >> 5;
        const int slot = f & 31;
        if (slot * 4 < ncols) {
            const float4 v = *reinterpret_cast<const float4*>(&ep[row * 128 + slot * 4]);
            *reinterpret_cast<float4*>(
                &out[(size_t)(m_base + row) * K_GMM + n_base + slot * 4]) = v;
        }
    }
}

extern "C" void kernel_launch(void* const* d_in, const int* in_sizes, int n_in,
                              void* d_out, int out_size, void* d_ws, size_t ws_size,
                              hipStream_t stream)
{
    (void)in_sizes; (void)n_in; (void)out_size; (void)ws_size;
    const float* X   = (const float*)d_in[0];
    const float* mu  = (const float*)d_in[1];
    const float* cov = (const float*)d_in[2];
    float* out = (float*)d_out;

    // workspace: W image = 512*1024 dwords (2 MiB), then bias[512] f32
    unsigned* Wimg = (unsigned*)d_ws;
    float*    bias = (float*)((char*)d_ws + (size_t)N_PAD * F_DIM * 4);

    prep_w_kernel<<<dim3(N_PAD), dim3(256), 0, stream>>>(mu, cov, Wimg, bias);
    gemm_kernel<<<dim3((M_TOT / BM) * (N_PAD / BN)), dim3(512), 0, stream>>>(X, Wimg, bias, out);
}